// Round 6
// baseline (1487.938 us; speedup 1.0000x reference)
//
#include <hip/hip_runtime.h>
#include <stdint.h>

// Problem constants (B=4, N=4096, D=512, K=16384, NUM_Q=2)
constexpr int TT = 16384;   // tokens = B*N
constexpr int DD = 512;     // feature dim
constexpr int KK = 16384;   // codebook size
constexpr int TOPK = 8;     // exact-rescore candidates per token

typedef __bf16 bf16x8 __attribute__((ext_vector_type(8)));
typedef __bf16 bf16x4 __attribute__((ext_vector_type(4)));
typedef float f32x4 __attribute__((ext_vector_type(4)));

typedef const __attribute__((address_space(1))) void* gas_ptr;
typedef __attribute__((address_space(3))) void* las_ptr;

// Monotone float -> sortable u32, packed with index. u64 min == (min dist, then min idx),
// matching np.argmin first-occurrence tie-break. (used in exact rescore)
__device__ __forceinline__ unsigned long long pack_di(float d, int idx) {
    uint32_t u = __float_as_uint(d);
    u = (u & 0x80000000u) ? ~u : (u | 0x80000000u);
    return ((unsigned long long)u << 32) | (uint32_t)idx;
}

__device__ __forceinline__ unsigned long long umin64(unsigned long long a,
                                                     unsigned long long b) {
    return a < b ? a : b;
}
__device__ __forceinline__ uint32_t umin32(uint32_t a, uint32_t b) { return a < b ? a : b; }
__device__ __forceinline__ uint32_t umax32(uint32_t a, uint32_t b) { return a > b ? a : b; }

// fp32 -> sortable u32 (monotone)
__device__ __forceinline__ uint32_t sortable(float d) {
    uint32_t u = __float_as_uint(d);
    return u ^ ((uint32_t)((int32_t)u >> 31) | 0x80000000u);
}

// ---------------------------------------------------------------------------
// bf16-MFMA GEMM with fp32-grade accuracy via hi/lo split (3 products):
//   out[m][n] = sum_k Ain[m][k] * W[n][k] + bias[n]
// MODE 0: Ain = A       ; writes out0 (z), out1 (r copy), out2 (bf16 z)
// MODE 1: Ain = A - A2  ; writes out0 only
// 128x128 tile, BK=64, 4 waves 4x1 (32 rows x 128 cols each). N = 512.
// ---------------------------------------------------------------------------
template<int MODE>
__global__ __launch_bounds__(256)
void gemm_mfma(const float* __restrict__ A, const float* __restrict__ A2,
               const float* __restrict__ W, const float* __restrict__ bias,
               float* __restrict__ out0, float* __restrict__ out1,
               __bf16* __restrict__ out2)
{
    __shared__ __bf16 Ah[128 * 64], Al[128 * 64];
    __shared__ __bf16 Bh[128 * 64], Bl[128 * 64];   // 64 KB total
    const int tid = threadIdx.x;
    const int lane = tid & 63;
    const int w = tid >> 6;
    const int row0 = blockIdx.y * 128;
    const int col0 = blockIdx.x * 128;

    f32x4 acc[2][8] = {};

    // staging coords: thread t covers (row = i*16 + t>>4, fp32 cols scol..scol+3)
    const int sr = tid >> 4;            // 0..15
    const int scol = (tid & 15) * 4;    // 0..60
    const int lcol = (((scol >> 3) ^ (sr & 7)) << 3) + (scol & 7);

    int a_off[2], b_off[8];
    #pragma unroll
    for (int mi = 0; mi < 2; ++mi) {
        const int ar = w * 32 + mi * 16 + (lane & 15);
        a_off[mi] = ar * 64 + (((lane >> 4) ^ (ar & 7)) << 3);
    }
    #pragma unroll
    for (int ni = 0; ni < 8; ++ni) {
        const int br = ni * 16 + (lane & 15);
        b_off[ni] = br * 64 + (((lane >> 4) ^ (br & 7)) << 3);
    }

    for (int kb = 0; kb < 512; kb += 64) {
        __syncthreads();
        #pragma unroll
        for (int i = 0; i < 8; ++i) {
            const int r = i * 16 + sr;
            float4 v = *(const float4*)(A + (size_t)(row0 + r) * 512 + kb + scol);
            if (MODE == 1) {
                const float4 u = *(const float4*)(A2 + (size_t)(row0 + r) * 512 + kb + scol);
                v.x -= u.x; v.y -= u.y; v.z -= u.z; v.w -= u.w;
            }
            bf16x4 hv, lv;
            hv[0] = (__bf16)v.x; hv[1] = (__bf16)v.y; hv[2] = (__bf16)v.z; hv[3] = (__bf16)v.w;
            lv[0] = (__bf16)(v.x - (float)hv[0]); lv[1] = (__bf16)(v.y - (float)hv[1]);
            lv[2] = (__bf16)(v.z - (float)hv[2]); lv[3] = (__bf16)(v.w - (float)hv[3]);
            *(bf16x4*)(Ah + r * 64 + lcol) = hv;
            *(bf16x4*)(Al + r * 64 + lcol) = lv;

            const float4 x = *(const float4*)(W + (size_t)(col0 + r) * 512 + kb + scol);
            bf16x4 hw, lw;
            hw[0] = (__bf16)x.x; hw[1] = (__bf16)x.y; hw[2] = (__bf16)x.z; hw[3] = (__bf16)x.w;
            lw[0] = (__bf16)(x.x - (float)hw[0]); lw[1] = (__bf16)(x.y - (float)hw[1]);
            lw[2] = (__bf16)(x.z - (float)hw[2]); lw[3] = (__bf16)(x.w - (float)hw[3]);
            *(bf16x4*)(Bh + r * 64 + lcol) = hw;
            *(bf16x4*)(Bl + r * 64 + lcol) = lw;
        }
        __syncthreads();
        #pragma unroll
        for (int s = 0; s < 2; ++s) {
            const int sx = s * 32;
            bf16x8 ah[2], al[2];
            #pragma unroll
            for (int mi = 0; mi < 2; ++mi) {
                ah[mi] = *(const bf16x8*)(Ah + (a_off[mi] ^ sx));
                al[mi] = *(const bf16x8*)(Al + (a_off[mi] ^ sx));
            }
            #pragma unroll
            for (int ni = 0; ni < 8; ++ni) {
                const bf16x8 bh = *(const bf16x8*)(Bh + (b_off[ni] ^ sx));
                const bf16x8 bl = *(const bf16x8*)(Bl + (b_off[ni] ^ sx));
                #pragma unroll
                for (int mi = 0; mi < 2; ++mi) {
                    acc[mi][ni] = __builtin_amdgcn_mfma_f32_16x16x32_bf16(ah[mi], bh, acc[mi][ni], 0, 0, 0);
                    acc[mi][ni] = __builtin_amdgcn_mfma_f32_16x16x32_bf16(ah[mi], bl, acc[mi][ni], 0, 0, 0);
                    acc[mi][ni] = __builtin_amdgcn_mfma_f32_16x16x32_bf16(al[mi], bh, acc[mi][ni], 0, 0, 0);
                }
            }
        }
    }

    #pragma unroll
    for (int mi = 0; mi < 2; ++mi) {
        #pragma unroll
        for (int reg = 0; reg < 4; ++reg) {
            const int row = row0 + w * 32 + mi * 16 + (lane >> 4) * 4 + reg;
            #pragma unroll
            for (int ni = 0; ni < 8; ++ni) {
                const int col = col0 + ni * 16 + (lane & 15);
                const float o = acc[mi][ni][reg] + bias[col];
                out0[(size_t)row * 512 + col] = o;
                if (MODE == 0) {
                    out1[(size_t)row * 512 + col] = o;
                    out2[(size_t)row * 512 + col] = (__bf16)o;
                }
            }
        }
    }
}

// ---------------------------------------------------------------------------
// Approx distance pass, 128x128 tile, A DIRECT-TO-REGISTER, B in LDS dbuf:
//   d[t][c] ~= csq[c] - 2 * (r16[t] . cb16[c])
// R5 post-mortem: 3 independent blocks/CU left MfmaUtil at 35% -- the shared
// per-CU LDS unit is the serialized resource (A+B stage writes + frag reads
// = 144 KB/step/CU ~ the 780-cyc/step wall). Fix: the 16x16x32 A-fragment
// (lane&15 = row, (lane>>4)*8 contiguous k) IS a per-lane 16 B slice of
// row-major r16 -- load A frags straight from L2 into registers, double-
// buffered across steps (no LDS, no barrier, no transpose). B keeps the
// proven LDS double-buffer (shared across wm -> dedup). LDS traffic/CU/step
// halves (144 -> 72 KB); LDS 16 KB/block.
// Per K-step: issue A(s+1) frags (4 global b128, pinned first) | read B(s)
// frags (4 ds_read_b128) | lgkm0 | BAR1 (licenses overwrite) | stage B(s+2)
// (2 global_load_lds) | 16 MFMA on A(s),B(s) | vmcnt(2) | BAR2.
// vmcnt ledger: queue at step start = [B(s+1):2]; after issues =
// [B(s+1):2, A(s+1):4, B(s+2):2]; vmcnt(2) retires exactly {B(s+1), A(s+1)}
// = next step's inputs, leaves B(s+2) in flight. Tail: stage skipped when
// s+2 >= NSTEP (then vmcnt(0)); A-issue skipped when s+1 >= NSTEP.
// Regs: acc 64 + afA/afB 32 + bfr 16 + addr/misc ~40 ~= 150 < 170 cap
// (launch_bounds(256,3)) -> 3 blocks/CU, no spill (R4 lesson).
// Grid/swizzle/epilogue unchanged from R5 (XCD stripe, CHAIN=8, top-2 keys).
// ---------------------------------------------------------------------------
constexpr int CHAIN = 8;                      // token tiles chained per block
constexpr int NSTEP = 16 * CHAIN;             // K-steps of 32 per block
constexpr size_t TILE_A = 128 * 512;          // elems per 128-row token tile

__global__ __launch_bounds__(256, 3)
void dist_approx4(const __bf16* __restrict__ Rh,   // [TT][512]
                  const __bf16* __restrict__ Ch,   // [KK][512]
                  const float* __restrict__ csq,
                  uint32_t* __restrict__ winners)
{
    __shared__ __bf16 Bs[2][128 * 32];   // 8 KB each -> 16 KB total

    const int tid  = threadIdx.x;
    const int lane = tid & 63;
    const int w    = tid >> 6;        // 0..3
    const int wm   = w >> 1;          // 0..1 : token half (64 rows)
    const int wn   = w & 1;           // 0..1 : code half (64 cols)

    // XCD column-stripe: xcd = b&7 owns code tiles [16*xcd, 16*xcd+16)
    const int b    = blockIdx.x;              // 0..2047
    const int xcd  = b & 7;
    const int i    = b >> 3;                  // 0..255
    const int ct   = xcd * 16 + (i & 15);     // code tile 0..127 (128 cols)
    const int tg   = i >> 4;                  // token group 0..15
    const int col0 = ct << 7;                 // code tile base
    const int rowb = tg << 10;                // 1024-token group base

    f32x4 acc[4][4] = {};   // [mi][ni] -- 64 regs

    // B staging coords: LDS linear for global_load_lds; swizzle on the GLOBAL
    // side. Thread covers row tid>>2 (0..63; +64 in 2nd load), physical chunk
    // tid&3 holding logical chunk (tid&3)^((row>>1)&3) (involution; rows +64
    // preserve the term).
    const int s_r = tid >> 2;                          // 0..63
    const int s_c = (tid & 3) ^ ((s_r >> 1) & 3);      // logical 16B chunk
    const __bf16* bS = Ch + (size_t)(col0 + s_r) * 512 + s_c * 8;
    __bf16* const lB0 = &Bs[0][0]; __bf16* const lB1 = &Bs[1][0];

    // A direct-to-reg fragment base: frag mi of step q is the 16 B at
    // aF + mi*16*512 + AOFF(q)  (row = rowb + tile*128 + wm*64 + mi*16 +
    // (lane&15), k = (q&15)*32 + (lane>>4)*8) -- exactly the MFMA A-fragment.
    const __bf16* aF = Rh + (size_t)(rowb + wm * 64 + (lane & 15)) * 512
                          + (lane >> 4) * 8;

    // A-source offset for K-step q (q = 0..NSTEP-1): tile (q>>4), k-block (q&15)
#define AOFF(q) ((size_t)((q) >> 4) * TILE_A + (size_t)((q) & 15) * 32)
#define BOFF(q) ((size_t)((q) & 15) * 32)

    // one B K-step panel (128 rows x 32 cols) = 2 x (256 thr x 16 B) = 8 KB
#define STAGEB(UOFF, DST)                                                          \
    {                                                                              \
        __builtin_amdgcn_global_load_lds((gas_ptr)(bS + (UOFF)),                   \
                                         (las_ptr)((DST) + w * 512), 16, 0, 0);    \
        __builtin_amdgcn_global_load_lds((gas_ptr)(bS + (UOFF) + 64 * 512),        \
                                         (las_ptr)((DST) + 64 * 32 + w * 512), 16, 0, 0); \
    }

    // B fragment LDS offsets (elems), swizzle-compensated
    int boff[4];
    #pragma unroll
    for (int ni = 0; ni < 4; ++ni) {
        const int r = wn * 64 + ni * 16 + (lane & 15);
        boff[ni] = r * 32 + ((((lane >> 4) ^ ((r >> 1) & 3))) << 3);
    }

#define BAR __builtin_amdgcn_s_barrier()
// full lgkm drain + scheduling fence: this wave's ds_reads have COMPLETED
// (data in VGPRs) before anything below (barrier / MFMA) runs.
#define LGKM0 { asm volatile("s_waitcnt lgkmcnt(0)" ::: "memory"); \
                __builtin_amdgcn_sched_barrier(0); }
#define MFMA16(AF, BV)                                                         \
    {                                                                          \
        __builtin_amdgcn_s_setprio(1);                                         \
        _Pragma("unroll")                                                      \
        for (int mi = 0; mi < 4; ++mi) {                                       \
            _Pragma("unroll")                                                  \
            for (int ni = 0; ni < 4; ++ni)                                     \
                acc[mi][ni] = __builtin_amdgcn_mfma_f32_16x16x32_bf16(         \
                    (AF)[mi], (BV)[ni], acc[mi][ni], 0, 0, 0);                 \
        }                                                                      \
        __builtin_amdgcn_s_setprio(0);                                         \
    }

// one K-step: AFC holds A(S) (loaded last step); AFN receives A(S+1).
#define STEP(LB, AFC, AFN, S)                                                  \
    {                                                                          \
        if ((S) + 1 < NSTEP) {                                                 \
            _Pragma("unroll")                                                  \
            for (int mi = 0; mi < 4; ++mi)                                     \
                (AFN)[mi] = *(const bf16x8*)(aF + (size_t)mi * (16 * 512)      \
                                              + AOFF((S) + 1));                \
            __builtin_amdgcn_sched_barrier(0);  /* pin A-issues first */       \
        }                                                                      \
        _Pragma("unroll")                                                      \
        for (int ni = 0; ni < 4; ++ni) bfr[ni] = *(const bf16x8*)((LB) + boff[ni]); \
        LGKM0;                                                                 \
        BAR;                                                                   \
        if ((S) + 2 < NSTEP) STAGEB(BOFF((S) + 2), (LB));                      \
        MFMA16(AFC, bfr);                                                      \
        if ((S) + 2 < NSTEP) { asm volatile("s_waitcnt vmcnt(2)" ::: "memory"); } \
        else                 { asm volatile("s_waitcnt vmcnt(0)" ::: "memory"); } \
        BAR;                                                                   \
    }

    // ---- csq hoist (col0 is block-invariant); drained by prologue vmcnt(0)
    float csv[4];
    #pragma unroll
    for (int ni = 0; ni < 4; ++ni)
        csv[ni] = csq[col0 + wn * 64 + ni * 16 + (lane & 15)];
    const int gt = (col0 >> 6) + wn;   // winners 64-col granule index (0..255)

    bf16x8 afA[4], afB[4], bfr[4];

    // ---- prologue: B(0)->buf0, B(1)->buf1, A(0) frags -> afA; drain all.
    STAGEB(BOFF(0), lB0);
    STAGEB(BOFF(1), lB1);
    #pragma unroll
    for (int mi = 0; mi < 4; ++mi)
        afA[mi] = *(const bf16x8*)(aF + (size_t)mi * (16 * 512) + AOFF(0));
    asm volatile("s_waitcnt vmcnt(0)" ::: "memory");
    BAR;

    for (int it = 0; it < 8 * CHAIN; ++it) {
        STEP(lB0, afA, afB, 2 * it);          // even step: B buffer 0
        STEP(lB1, afB, afA, 2 * it + 1);      // odd step:  B buffer 1

        // ---- per-tile epilogue: token tile finished every 8 iterations.
        // Top-2 over this wave's 64 cols, u32 keys; C/D layout (16x16x32):
        // col = lane&15, row = (lane>>4)*4 + reg.  Then re-zero acc.
        // Winner stores enter the vmcnt queue as OLDER ops than the next
        // step's issues; the next vmcnt(2) retires them too (conservative,
        // never unsafe).
        if ((it & 7) == 7) {
            const int r0t = rowb + (it >> 3) * 128;
            #pragma unroll
            for (int mi = 0; mi < 4; ++mi) {
                #pragma unroll
                for (int reg = 0; reg < 4; ++reg) {
                    uint32_t bk = 0xFFFFFFFFu, sk = 0xFFFFFFFFu;
                    #pragma unroll
                    for (int ni = 0; ni < 4; ++ni) {
                        const float d = fmaf(-2.0f, acc[mi][ni][reg], csv[ni]);
                        const uint32_t key = (sortable(d) & 0xFFFFFFC0u)
                                           | (uint32_t)(ni * 16 + (lane & 15));
                        const uint32_t nb = umin32(bk, key);
                        sk = umin32(sk, umax32(bk, key));
                        bk = nb;
                    }
                    #pragma unroll
                    for (int m = 1; m < 16; m <<= 1) {
                        const uint32_t ob = __shfl_xor((int)bk, m, 16);
                        const uint32_t os = __shfl_xor((int)sk, m, 16);
                        const uint32_t nb = umin32(bk, ob);
                        sk = umin32(umin32(sk, os), umax32(bk, ob));
                        bk = nb;
                    }
                    if ((lane & 15) == 0) {
                        const int row = r0t + wm * 64 + mi * 16 + (lane >> 4) * 4 + reg;
                        uint2 v; v.x = bk; v.y = sk;
                        *(uint2*)(winners + (size_t)row * 512 + gt * 2) = v;
                    }
                }
            }
            #pragma unroll
            for (int mi = 0; mi < 4; ++mi)
                #pragma unroll
                for (int ni = 0; ni < 4; ++ni)
                    acc[mi][ni] = (f32x4){0.f, 0.f, 0.f, 0.f};
        }
    }
#undef STEP
#undef STAGEB
#undef AOFF
#undef BOFF
#undef BAR
#undef LGKM0
#undef MFMA16
}

// ---------------------------------------------------------------------------
// Per token (one wave): approx top-8 of the 512 stored u32 keys, exact fp32
// rescore, pick true argmin (np tie-break), then fused residual update:
//   r[t] -= cb[best];  r16[t] = bf16(r[t])
// key -> global col: slot j holds tile j>>1 (64-col granule), col low 6 bits.
// ---------------------------------------------------------------------------
__global__ __launch_bounds__(256)
void select_rescore(const uint32_t* __restrict__ winners,
                    const float* __restrict__ CB, const float* __restrict__ csq,
                    float* __restrict__ R, __bf16* __restrict__ R16)
{
    const int w = threadIdx.x >> 6;
    const int lane = threadIdx.x & 63;
    const int token = blockIdx.x * 4 + w;

    const uint32_t* wt = winners + (size_t)token * 512;
    uint4 q0 = *(const uint4*)(wt + lane * 8);
    uint4 q1 = *(const uint4*)(wt + lane * 8 + 4);
    uint32_t k32[8] = {q0.x, q0.y, q0.z, q0.w, q1.x, q1.y, q1.z, q1.w};

    unsigned long long v[8];
    #pragma unroll
    for (int j = 0; j < 8; ++j) {
        const int gcol = ((lane * 8 + j) >> 1) * 64 + (int)(k32[j] & 63u);
        v[j] = ((unsigned long long)k32[j] << 32) | (uint32_t)gcol;
    }

    unsigned long long cand[TOPK];
    #pragma unroll
    for (int t = 0; t < TOPK; ++t) {
        unsigned long long mm = v[0];
        #pragma unroll
        for (int j = 1; j < 8; ++j) mm = umin64(mm, v[j]);
        #pragma unroll
        for (int m = 1; m < 64; m <<= 1)
            mm = umin64(mm, __shfl_xor(mm, m, 64));
        cand[t] = mm;
        #pragma unroll
        for (int j = 0; j < 8; ++j) if (v[j] == mm) v[j] = ~0ull;
    }

    // exact rescore in fp32
    float4 r0 = *(const float4*)(R + (size_t)token * 512 + lane * 8);
    float4 r1 = *(const float4*)(R + (size_t)token * 512 + lane * 8 + 4);

    unsigned long long best = ~0ull;
    #pragma unroll
    for (int t = 0; t < TOPK; ++t) {
        const int col = (int)(cand[t] & 0xFFFFFFFFull);
        const float4 c0 = *(const float4*)(CB + (size_t)col * 512 + lane * 8);
        const float4 c1 = *(const float4*)(CB + (size_t)col * 512 + lane * 8 + 4);
        float dot = r0.x * c0.x;
        dot = fmaf(r0.y, c0.y, dot); dot = fmaf(r0.z, c0.z, dot);
        dot = fmaf(r0.w, c0.w, dot); dot = fmaf(r1.x, c1.x, dot);
        dot = fmaf(r1.y, c1.y, dot); dot = fmaf(r1.z, c1.z, dot);
        dot = fmaf(r1.w, c1.w, dot);
        #pragma unroll
        for (int m = 1; m < 64; m <<= 1) dot += __shfl_xor(dot, m, 64);
        const float d = fmaf(-2.0f, dot, csq[col]);
        best = umin64(best, pack_di(d, col));
    }

    const int bcol = (int)(best & 0xFFFFFFFFull);
    const float4 c0 = *(const float4*)(CB + (size_t)bcol * 512 + lane * 8);
    const float4 c1 = *(const float4*)(CB + (size_t)bcol * 512 + lane * 8 + 4);
    r0.x -= c0.x; r0.y -= c0.y; r0.z -= c0.z; r0.w -= c0.w;
    r1.x -= c1.x; r1.y -= c1.y; r1.z -= c1.z; r1.w -= c1.w;
    *(float4*)(R + (size_t)token * 512 + lane * 8) = r0;
    *(float4*)(R + (size_t)token * 512 + lane * 8 + 4) = r1;
    bf16x8 h;
    h[0] = (__bf16)r0.x; h[1] = (__bf16)r0.y; h[2] = (__bf16)r0.z; h[3] = (__bf16)r0.w;
    h[4] = (__bf16)r1.x; h[5] = (__bf16)r1.y; h[6] = (__bf16)r1.z; h[7] = (__bf16)r1.w;
    *(bf16x8*)(R16 + (size_t)token * 512 + lane * 8) = h;
}

// ---------------------------------------------------------------------------
// Codebook prep (fused): c_sq[k] = ||cb[k]||^2 (fp32) and cb16 = bf16(cb)
// ---------------------------------------------------------------------------
__global__ __launch_bounds__(256)
void prep_cb(const float* __restrict__ CB, float* __restrict__ c_sq,
             __bf16* __restrict__ cb16)
{
    const int wave = threadIdx.x >> 6;
    const int lane = threadIdx.x & 63;
    const int row = blockIdx.x * 4 + wave;
    const float* p = CB + (size_t)row * DD + lane * 8;
    const float4 a = *(const float4*)p;
    const float4 b = *(const float4*)(p + 4);
    bf16x8 h;
    h[0] = (__bf16)a.x; h[1] = (__bf16)a.y; h[2] = (__bf16)a.z; h[3] = (__bf16)a.w;
    h[4] = (__bf16)b.x; h[5] = (__bf16)b.y; h[6] = (__bf16)b.z; h[7] = (__bf16)b.w;
    *(bf16x8*)(cb16 + (size_t)row * DD + lane * 8) = h;
    float s = a.x*a.x + a.y*a.y + a.z*a.z + a.w*a.w
            + b.x*b.x + b.y*b.y + b.z*b.z + b.w*b.w;
    #pragma unroll
    for (int m = 1; m < 64; m <<= 1) s += __shfl_xor(s, m, 64);
    if (lane == 0) c_sq[row] = s;
}

// ---------------------------------------------------------------------------
extern "C" void kernel_launch(void* const* d_in, const int* in_sizes, int n_in,
                              void* d_out, int out_size, void* d_ws, size_t ws_size,
                              hipStream_t stream)
{
    const float* x    = (const float*)d_in[0];
    const float* encw = (const float*)d_in[1];
    const float* encb = (const float*)d_in[2];
    const float* cb   = (const float*)d_in[3];
    const float* decw = (const float*)d_in[4];
    const float* decb = (const float*)d_in[5];
    float* out = (float*)d_out;

    // ws layout: z (32MB) | r (32MB) | cb16 (16MB) | r16 (16MB) | csq  (~96.1MB)
    float* z    = (float*)d_ws;                                  // TT*DD f32
    float* r    = z + (size_t)TT * DD;                           // TT*DD f32
    __bf16* cb16 = (__bf16*)(r + (size_t)TT * DD);               // KK*512 bf16
    __bf16* r16  = cb16 + (size_t)KK * DD;                       // TT*512 bf16
    float* csq  = (float*)(r16 + (size_t)TT * DD);               // KK f32
    // winners table lives in d_out (33.5 MB) — dead before decoder writes out
    uint32_t* winners = (uint32_t*)d_out;                        // TT*512 u32

    const dim3 blk(256);

    // encoder (MFMA hi/lo): z = x @ enc_w^T + enc_b ; r = z ; r16 = bf16(z)
    gemm_mfma<0><<<dim3(DD / 128, TT / 128), blk, 0, stream>>>(
        x, nullptr, encw, encb, z, r, r16);

    // codebook: exact squared norms + bf16 copy (fused, once per call)
    prep_cb<<<dim3(KK / 4), blk, 0, stream>>>(cb, csq, cb16);

    for (int s = 0; s < 2; ++s) {
        // 2048 blocks = 128 code-tiles x 16 token-groups (CHAIN=8 tiles each);
        // 16 KB LDS + <=170 regs -> 3 blocks/CU, A direct-to-reg from L2.
        dist_approx4<<<dim3((KK / 128) * (TT / 128 / CHAIN)), dim3(256), 0, stream>>>(
            r16, cb16, csq, winners);
        select_rescore<<<dim3(TT / 4), blk, 0, stream>>>(winners, cb, csq, r, r16);
    }

    // decoder (MFMA hi/lo): out = (z - r) @ dec_w^T + dec_b
    gemm_mfma<1><<<dim3(DD / 128, TT / 128), blk, 0, stream>>>(
        z, r, decw, decb, out, nullptr, nullptr);
}

// Round 7
// 1100.469 us; speedup vs baseline: 1.3521x; 1.3521x over previous
//
#include <hip/hip_runtime.h>
#include <stdint.h>

// Problem constants (B=4, N=4096, D=512, K=16384, NUM_Q=2)
constexpr int TT = 16384;   // tokens = B*N
constexpr int DD = 512;     // feature dim
constexpr int KK = 16384;   // codebook size
constexpr int TOPK = 8;     // exact-rescore candidates per token

typedef __bf16 bf16x8 __attribute__((ext_vector_type(8)));
typedef __bf16 bf16x4 __attribute__((ext_vector_type(4)));
typedef float f32x4 __attribute__((ext_vector_type(4)));

typedef const __attribute__((address_space(1))) void* gas_ptr;
typedef __attribute__((address_space(3))) void* las_ptr;

// ---------------------------------------------------------------------------
// r16 FRAGMENT-MAJOR layout: the MFMA 16x16x32 A-fragment for (16-row group,
// 32-k chunk) is stored as one contiguous 1 KB block whose 16 B lane-slot
// index equals the MFMA lane: slot = ((k>>3)&3)*16 + (row&15)  (= lane, since
// A-operand lane l supplies row l&15, k-bytes (l>>4)*8..+8).
//   elem(row,k) -> ((row>>4)*16 + (k>>5))*512 + (((k>>3)&3)*16 + (row&15))*8
//                  + (k&7)
// Written by gemm_mfma<0> epilogue + select_rescore; read by dist_approx4 as
// ONE fully-coalesced 1 KB global load per fragment (R6's 16-segment scatter
// was the regression cause).
// ---------------------------------------------------------------------------
__device__ __forceinline__ size_t frag_off(int row, int k) {
    return ((size_t)(row >> 4) * 16 + (k >> 5)) * 512
         + (((k >> 3) & 3) * 16 + (row & 15)) * 8 + (k & 7);
}

// Monotone float -> sortable u32, packed with index. u64 min == (min dist, then min idx),
// matching np.argmin first-occurrence tie-break. (used in exact rescore)
__device__ __forceinline__ unsigned long long pack_di(float d, int idx) {
    uint32_t u = __float_as_uint(d);
    u = (u & 0x80000000u) ? ~u : (u | 0x80000000u);
    return ((unsigned long long)u << 32) | (uint32_t)idx;
}

__device__ __forceinline__ unsigned long long umin64(unsigned long long a,
                                                     unsigned long long b) {
    return a < b ? a : b;
}
__device__ __forceinline__ uint32_t umin32(uint32_t a, uint32_t b) { return a < b ? a : b; }
__device__ __forceinline__ uint32_t umax32(uint32_t a, uint32_t b) { return a > b ? a : b; }

// fp32 -> sortable u32 (monotone)
__device__ __forceinline__ uint32_t sortable(float d) {
    uint32_t u = __float_as_uint(d);
    return u ^ ((uint32_t)((int32_t)u >> 31) | 0x80000000u);
}

// ---------------------------------------------------------------------------
// bf16-MFMA GEMM with fp32-grade accuracy via hi/lo split (3 products):
//   out[m][n] = sum_k Ain[m][k] * W[n][k] + bias[n]
// MODE 0: Ain = A       ; writes out0 (z), out1 (r copy), out2 (bf16 z,
//                          FRAGMENT-MAJOR layout)
// MODE 1: Ain = A - A2  ; writes out0 only
// 128x128 tile, BK=64, 4 waves 4x1 (32 rows x 128 cols each). N = 512.
// ---------------------------------------------------------------------------
template<int MODE>
__global__ __launch_bounds__(256)
void gemm_mfma(const float* __restrict__ A, const float* __restrict__ A2,
               const float* __restrict__ W, const float* __restrict__ bias,
               float* __restrict__ out0, float* __restrict__ out1,
               __bf16* __restrict__ out2)
{
    __shared__ __bf16 Ah[128 * 64], Al[128 * 64];
    __shared__ __bf16 Bh[128 * 64], Bl[128 * 64];   // 64 KB total
    const int tid = threadIdx.x;
    const int lane = tid & 63;
    const int w = tid >> 6;
    const int row0 = blockIdx.y * 128;
    const int col0 = blockIdx.x * 128;

    f32x4 acc[2][8] = {};

    // staging coords: thread t covers (row = i*16 + t>>4, fp32 cols scol..scol+3)
    const int sr = tid >> 4;            // 0..15
    const int scol = (tid & 15) * 4;    // 0..60
    const int lcol = (((scol >> 3) ^ (sr & 7)) << 3) + (scol & 7);

    int a_off[2], b_off[8];
    #pragma unroll
    for (int mi = 0; mi < 2; ++mi) {
        const int ar = w * 32 + mi * 16 + (lane & 15);
        a_off[mi] = ar * 64 + (((lane >> 4) ^ (ar & 7)) << 3);
    }
    #pragma unroll
    for (int ni = 0; ni < 8; ++ni) {
        const int br = ni * 16 + (lane & 15);
        b_off[ni] = br * 64 + (((lane >> 4) ^ (br & 7)) << 3);
    }

    for (int kb = 0; kb < 512; kb += 64) {
        __syncthreads();
        #pragma unroll
        for (int i = 0; i < 8; ++i) {
            const int r = i * 16 + sr;
            float4 v = *(const float4*)(A + (size_t)(row0 + r) * 512 + kb + scol);
            if (MODE == 1) {
                const float4 u = *(const float4*)(A2 + (size_t)(row0 + r) * 512 + kb + scol);
                v.x -= u.x; v.y -= u.y; v.z -= u.z; v.w -= u.w;
            }
            bf16x4 hv, lv;
            hv[0] = (__bf16)v.x; hv[1] = (__bf16)v.y; hv[2] = (__bf16)v.z; hv[3] = (__bf16)v.w;
            lv[0] = (__bf16)(v.x - (float)hv[0]); lv[1] = (__bf16)(v.y - (float)hv[1]);
            lv[2] = (__bf16)(v.z - (float)hv[2]); lv[3] = (__bf16)(v.w - (float)hv[3]);
            *(bf16x4*)(Ah + r * 64 + lcol) = hv;
            *(bf16x4*)(Al + r * 64 + lcol) = lv;

            const float4 x = *(const float4*)(W + (size_t)(col0 + r) * 512 + kb + scol);
            bf16x4 hw, lw;
            hw[0] = (__bf16)x.x; hw[1] = (__bf16)x.y; hw[2] = (__bf16)x.z; hw[3] = (__bf16)x.w;
            lw[0] = (__bf16)(x.x - (float)hw[0]); lw[1] = (__bf16)(x.y - (float)hw[1]);
            lw[2] = (__bf16)(x.z - (float)hw[2]); lw[3] = (__bf16)(x.w - (float)hw[3]);
            *(bf16x4*)(Bh + r * 64 + lcol) = hw;
            *(bf16x4*)(Bl + r * 64 + lcol) = lw;
        }
        __syncthreads();
        #pragma unroll
        for (int s = 0; s < 2; ++s) {
            const int sx = s * 32;
            bf16x8 ah[2], al[2];
            #pragma unroll
            for (int mi = 0; mi < 2; ++mi) {
                ah[mi] = *(const bf16x8*)(Ah + (a_off[mi] ^ sx));
                al[mi] = *(const bf16x8*)(Al + (a_off[mi] ^ sx));
            }
            #pragma unroll
            for (int ni = 0; ni < 8; ++ni) {
                const bf16x8 bh = *(const bf16x8*)(Bh + (b_off[ni] ^ sx));
                const bf16x8 bl = *(const bf16x8*)(Bl + (b_off[ni] ^ sx));
                #pragma unroll
                for (int mi = 0; mi < 2; ++mi) {
                    acc[mi][ni] = __builtin_amdgcn_mfma_f32_16x16x32_bf16(ah[mi], bh, acc[mi][ni], 0, 0, 0);
                    acc[mi][ni] = __builtin_amdgcn_mfma_f32_16x16x32_bf16(ah[mi], bl, acc[mi][ni], 0, 0, 0);
                    acc[mi][ni] = __builtin_amdgcn_mfma_f32_16x16x32_bf16(al[mi], bh, acc[mi][ni], 0, 0, 0);
                }
            }
        }
    }

    #pragma unroll
    for (int mi = 0; mi < 2; ++mi) {
        #pragma unroll
        for (int reg = 0; reg < 4; ++reg) {
            const int row = row0 + w * 32 + mi * 16 + (lane >> 4) * 4 + reg;
            #pragma unroll
            for (int ni = 0; ni < 8; ++ni) {
                const int col = col0 + ni * 16 + (lane & 15);
                const float o = acc[mi][ni][reg] + bias[col];
                out0[(size_t)row * 512 + col] = o;
                if (MODE == 0) {
                    out1[(size_t)row * 512 + col] = o;
                    out2[frag_off(row, col)] = (__bf16)o;   // fragment-major
                }
            }
        }
    }
}

// ---------------------------------------------------------------------------
// Approx distance pass, 128x128 tile, A DIRECT-TO-REG (fragment-major,
// fully coalesced), B in LDS dbuf, BK=32:
//   d[t][c] ~= csq[c] - 2 * (r16[t] . cb16[c])
// R6 post-mortem: A-direct was right, addressing was wrong (16 scattered
// 64 B segments/load). With r16 fragment-major, each A-frag is ONE coalesced
// 1 KB load (lane l reads base + l*16). LDS now carries only B: per CU-step
// traffic 144 -> 72 KB (the R5 wall), LDS 16 KB/block, 3 blocks/CU.
// Per K-step s:
//   1. read B(s) frags (4 ds_read_b128)   2. lgkm0 + sched fence
//   3. BAR (licenses overwrite)           4. stage B(s+2) (2 gl_lds)
//   5. MFMA16(af[s&1], bfr)               6. issue A(s+2) -> af[s&1]
//      (WAR on regs orders 6 after 5; in-flight window ~1 full step > L2 lat)
//   7. vmcnt(6); BAR.
// vmcnt ledger: start-of-step outstanding = [B(s+1):2, A(s+1):4]; after 4,6:
// +[B(s+2):2, A(s+2):4] = 12; vmcnt(6) retires exactly {B(s+1), A(s+1)} =
// next step's inputs. Prologue: A(0):4,B(0):2,A(1):4,B(1):2 then vmcnt(6)
// retires {A(0),B(0)}. Tail (s+2>=NSTEP): no issues, vmcnt(0).
// Epilogue winner stores enter the queue as older ops; later vmcnt(6) waits
// retire them too (conservative, never unsafe).
// Regs: acc 64 + af 2x16 + bfr 16 + addr ~30 ~= 145 < 170 cap (256,3).
// Grid/swizzle/epilogue unchanged from R5 (XCD stripe, CHAIN=8, top-2 keys).
// ---------------------------------------------------------------------------
constexpr int CHAIN = 8;                      // token tiles chained per block
constexpr int NSTEP = 16 * CHAIN;             // K-steps of 32 per block

__global__ __launch_bounds__(256, 3)
void dist_approx4(const __bf16* __restrict__ Rh,   // [TT][512] fragment-major
                  const __bf16* __restrict__ Ch,   // [KK][512] row-major
                  const float* __restrict__ csq,
                  uint32_t* __restrict__ winners)
{
    __shared__ __bf16 Bs[2][128 * 32];   // 8 KB each -> 16 KB total

    const int tid  = threadIdx.x;
    const int lane = tid & 63;
    const int w    = tid >> 6;        // 0..3
    const int wm   = w >> 1;          // 0..1 : token half (64 rows)
    const int wn   = w & 1;           // 0..1 : code half (64 cols)

    // XCD column-stripe: xcd = b&7 owns code tiles [16*xcd, 16*xcd+16)
    const int b    = blockIdx.x;              // 0..2047
    const int xcd  = b & 7;
    const int i    = b >> 3;                  // 0..255
    const int ct   = xcd * 16 + (i & 15);     // code tile 0..127 (128 cols)
    const int tg   = i >> 4;                  // token group 0..15
    const int col0 = ct << 7;                 // code tile base
    const int rowb = tg << 10;                // 1024-token group base

    f32x4 acc[4][4] = {};   // [mi][ni] -- 64 regs

    // B staging coords: LDS linear for global_load_lds; swizzle on the GLOBAL
    // side. Thread covers row tid>>2 (0..63; +64 in 2nd load), physical chunk
    // tid&3 holding logical chunk (tid&3)^((row>>1)&3) (involution; rows +64
    // preserve the term).
    const int s_r = tid >> 2;                          // 0..63
    const int s_c = (tid & 3) ^ ((s_r >> 1) & 3);      // logical 16B chunk
    const __bf16* bS = Ch + (size_t)(col0 + s_r) * 512 + s_c * 8;
    __bf16* const lB0 = &Bs[0][0]; __bf16* const lB1 = &Bs[1][0];

    // A fragment-major base: frag (q, mi) = 1 KB block at row-group
    // tg*64 + (q>>4)*8 + wm*4 + mi, k-chunk q&15; lane slot = lane*16 B.
    const __bf16* aF = Rh + lane * 8;
#define AFOFF(q, mi) (((size_t)(tg * 1024 + ((q) >> 4) * 128 + wm * 64 \
                                + (mi) * 16 + ((q) & 15))) * 512)
#define BOFF(q) ((size_t)((q) & 15) * 32)

    // one B K-step panel (128 rows x 32 cols) = 2 x (256 thr x 16 B) = 8 KB
#define STAGEB(UOFF, DST)                                                          \
    {                                                                              \
        __builtin_amdgcn_global_load_lds((gas_ptr)(bS + (UOFF)),                   \
                                         (las_ptr)((DST) + w * 512), 16, 0, 0);    \
        __builtin_amdgcn_global_load_lds((gas_ptr)(bS + (UOFF) + 64 * 512),        \
                                         (las_ptr)((DST) + 64 * 32 + w * 512), 16, 0, 0); \
    }

    // B fragment LDS offsets (elems), swizzle-compensated
    int boff[4];
    #pragma unroll
    for (int ni = 0; ni < 4; ++ni) {
        const int r = wn * 64 + ni * 16 + (lane & 15);
        boff[ni] = r * 32 + ((((lane >> 4) ^ ((r >> 1) & 3))) << 3);
    }

#define BAR __builtin_amdgcn_s_barrier()
// full lgkm drain + scheduling fence: this wave's ds_reads have COMPLETED
// (data in VGPRs) before anything below (barrier / MFMA) runs.
#define LGKM0 { asm volatile("s_waitcnt lgkmcnt(0)" ::: "memory"); \
                __builtin_amdgcn_sched_barrier(0); }
#define MFMA16(AF, BV)                                                         \
    {                                                                          \
        __builtin_amdgcn_s_setprio(1);                                         \
        _Pragma("unroll")                                                      \
        for (int mi = 0; mi < 4; ++mi) {                                       \
            _Pragma("unroll")                                                  \
            for (int ni = 0; ni < 4; ++ni)                                     \
                acc[mi][ni] = __builtin_amdgcn_mfma_f32_16x16x32_bf16(         \
                    (AF)[mi], (BV)[ni], acc[mi][ni], 0, 0, 0);                 \
        }                                                                      \
        __builtin_amdgcn_s_setprio(0);                                         \
    }

// one K-step; AFC = af[s&1] holds A(s), refilled with A(s+2) after the MFMAs.
#define STEP(LB, AFC, S)                                                       \
    {                                                                          \
        _Pragma("unroll")                                                      \
        for (int ni = 0; ni < 4; ++ni) bfr[ni] = *(const bf16x8*)((LB) + boff[ni]); \
        LGKM0;                                                                 \
        BAR;                                                                   \
        if ((S) + 2 < NSTEP) STAGEB(BOFF((S) + 2), (LB));                      \
        MFMA16(AFC, bfr);                                                      \
        if ((S) + 2 < NSTEP) {                                                 \
            _Pragma("unroll")                                                  \
            for (int mi = 0; mi < 4; ++mi)                                     \
                (AFC)[mi] = *(const bf16x8*)(aF + AFOFF((S) + 2, mi));         \
            asm volatile("s_waitcnt vmcnt(6)" ::: "memory");                   \
        } else {                                                               \
            asm volatile("s_waitcnt vmcnt(0)" ::: "memory");                   \
        }                                                                      \
        BAR;                                                                   \
    }

    // ---- csq hoist (col0 is block-invariant); oldest vm ops, retired by
    // the prologue vmcnt(6).
    float csv[4];
    #pragma unroll
    for (int ni = 0; ni < 4; ++ni)
        csv[ni] = csq[col0 + wn * 64 + ni * 16 + (lane & 15)];
    const int gt = (col0 >> 6) + wn;   // winners 64-col granule index (0..255)

    bf16x8 af0[4], af1[4], bfr[4];

    // ---- prologue: A(0)->af0, B(0)->buf0, A(1)->af1, B(1)->buf1;
    // vmcnt(6) retires {csq, A(0), B(0)} leaving [A(1):4, B(1):2] in flight.
    #pragma unroll
    for (int mi = 0; mi < 4; ++mi)
        af0[mi] = *(const bf16x8*)(aF + AFOFF(0, mi));
    STAGEB(BOFF(0), lB0);
    #pragma unroll
    for (int mi = 0; mi < 4; ++mi)
        af1[mi] = *(const bf16x8*)(aF + AFOFF(1, mi));
    STAGEB(BOFF(1), lB1);
    asm volatile("s_waitcnt vmcnt(6)" ::: "memory");
    BAR;

    for (int it = 0; it < 8 * CHAIN; ++it) {
        STEP(lB0, af0, 2 * it);          // even step: B buffer 0, A set 0
        STEP(lB1, af1, 2 * it + 1);      // odd step:  B buffer 1, A set 1

        // ---- per-tile epilogue: token tile finished every 8 iterations
        // (16 K-steps). Top-2 over this wave's 64 cols, u32 keys; C/D layout
        // (16x16x32): col = lane&15, row = (lane>>4)*4 + reg. Re-zero acc.
        if ((it & 7) == 7) {
            const int r0t = rowb + (it >> 3) * 128;
            #pragma unroll
            for (int mi = 0; mi < 4; ++mi) {
                #pragma unroll
                for (int reg = 0; reg < 4; ++reg) {
                    uint32_t bk = 0xFFFFFFFFu, sk = 0xFFFFFFFFu;
                    #pragma unroll
                    for (int ni = 0; ni < 4; ++ni) {
                        const float d = fmaf(-2.0f, acc[mi][ni][reg], csv[ni]);
                        const uint32_t key = (sortable(d) & 0xFFFFFFC0u)
                                           | (uint32_t)(ni * 16 + (lane & 15));
                        const uint32_t nb = umin32(bk, key);
                        sk = umin32(sk, umax32(bk, key));
                        bk = nb;
                    }
                    #pragma unroll
                    for (int m = 1; m < 16; m <<= 1) {
                        const uint32_t ob = __shfl_xor((int)bk, m, 16);
                        const uint32_t os = __shfl_xor((int)sk, m, 16);
                        const uint32_t nb = umin32(bk, ob);
                        sk = umin32(umin32(sk, os), umax32(bk, ob));
                        bk = nb;
                    }
                    if ((lane & 15) == 0) {
                        const int row = r0t + wm * 64 + mi * 16 + (lane >> 4) * 4 + reg;
                        uint2 v; v.x = bk; v.y = sk;
                        *(uint2*)(winners + (size_t)row * 512 + gt * 2) = v;
                    }
                }
            }
            #pragma unroll
            for (int mi = 0; mi < 4; ++mi)
                #pragma unroll
                for (int ni = 0; ni < 4; ++ni)
                    acc[mi][ni] = (f32x4){0.f, 0.f, 0.f, 0.f};
        }
    }
#undef STEP
#undef STAGEB
#undef AFOFF
#undef BOFF
#undef BAR
#undef LGKM0
#undef MFMA16
}

// ---------------------------------------------------------------------------
// Per token (one wave): approx top-8 of the 512 stored u32 keys, exact fp32
// rescore, pick true argmin (np tie-break), then fused residual update:
//   r[t] -= cb[best];  r16[t] = bf16(r[t])  (fragment-major write)
// key -> global col: slot j holds tile j>>1 (64-col granule), col low 6 bits.
// ---------------------------------------------------------------------------
__global__ __launch_bounds__(256)
void select_rescore(const uint32_t* __restrict__ winners,
                    const float* __restrict__ CB, const float* __restrict__ csq,
                    float* __restrict__ R, __bf16* __restrict__ R16)
{
    const int w = threadIdx.x >> 6;
    const int lane = threadIdx.x & 63;
    const int token = blockIdx.x * 4 + w;

    const uint32_t* wt = winners + (size_t)token * 512;
    uint4 q0 = *(const uint4*)(wt + lane * 8);
    uint4 q1 = *(const uint4*)(wt + lane * 8 + 4);
    uint32_t k32[8] = {q0.x, q0.y, q0.z, q0.w, q1.x, q1.y, q1.z, q1.w};

    unsigned long long v[8];
    #pragma unroll
    for (int j = 0; j < 8; ++j) {
        const int gcol = ((lane * 8 + j) >> 1) * 64 + (int)(k32[j] & 63u);
        v[j] = ((unsigned long long)k32[j] << 32) | (uint32_t)gcol;
    }

    unsigned long long cand[TOPK];
    #pragma unroll
    for (int t = 0; t < TOPK; ++t) {
        unsigned long long mm = v[0];
        #pragma unroll
        for (int j = 1; j < 8; ++j) mm = umin64(mm, v[j]);
        #pragma unroll
        for (int m = 1; m < 64; m <<= 1)
            mm = umin64(mm, __shfl_xor(mm, m, 64));
        cand[t] = mm;
        #pragma unroll
        for (int j = 0; j < 8; ++j) if (v[j] == mm) v[j] = ~0ull;
    }

    // exact rescore in fp32
    float4 r0 = *(const float4*)(R + (size_t)token * 512 + lane * 8);
    float4 r1 = *(const float4*)(R + (size_t)token * 512 + lane * 8 + 4);

    unsigned long long best = ~0ull;
    #pragma unroll
    for (int t = 0; t < TOPK; ++t) {
        const int col = (int)(cand[t] & 0xFFFFFFFFull);
        const float4 c0 = *(const float4*)(CB + (size_t)col * 512 + lane * 8);
        const float4 c1 = *(const float4*)(CB + (size_t)col * 512 + lane * 8 + 4);
        float dot = r0.x * c0.x;
        dot = fmaf(r0.y, c0.y, dot); dot = fmaf(r0.z, c0.z, dot);
        dot = fmaf(r0.w, c0.w, dot); dot = fmaf(r1.x, c1.x, dot);
        dot = fmaf(r1.y, c1.y, dot); dot = fmaf(r1.z, c1.z, dot);
        dot = fmaf(r1.w, c1.w, dot);
        #pragma unroll
        for (int m = 1; m < 64; m <<= 1) dot += __shfl_xor(dot, m, 64);
        const float d = fmaf(-2.0f, dot, csq[col]);
        best = umin64(best, pack_di(d, col));
    }

    const int bcol = (int)(best & 0xFFFFFFFFull);
    const float4 c0 = *(const float4*)(CB + (size_t)bcol * 512 + lane * 8);
    const float4 c1 = *(const float4*)(CB + (size_t)bcol * 512 + lane * 8 + 4);
    r0.x -= c0.x; r0.y -= c0.y; r0.z -= c0.z; r0.w -= c0.w;
    r1.x -= c1.x; r1.y -= c1.y; r1.z -= c1.z; r1.w -= c1.w;
    *(float4*)(R + (size_t)token * 512 + lane * 8) = r0;
    *(float4*)(R + (size_t)token * 512 + lane * 8 + 4) = r1;
    bf16x8 h;
    h[0] = (__bf16)r0.x; h[1] = (__bf16)r0.y; h[2] = (__bf16)r0.z; h[3] = (__bf16)r0.w;
    h[4] = (__bf16)r1.x; h[5] = (__bf16)r1.y; h[6] = (__bf16)r1.z; h[7] = (__bf16)r1.w;
    // fragment-major: token row fixed; lane covers k = lane*8..lane*8+7,
    // one contiguous 16 B slot at ((token>>4)*16 + (lane>>2))*512
    //                             + ((lane&3)*16 + (token&15))*8
    const size_t fo = ((size_t)(token >> 4) * 16 + (lane >> 2)) * 512
                    + (size_t)((lane & 3) * 16 + (token & 15)) * 8;
    *(bf16x8*)(R16 + fo) = h;
}

// ---------------------------------------------------------------------------
// Codebook prep (fused): c_sq[k] = ||cb[k]||^2 (fp32) and cb16 = bf16(cb)
// (cb16 stays ROW-major: it is the B operand, still staged via LDS.)
// ---------------------------------------------------------------------------
__global__ __launch_bounds__(256)
void prep_cb(const float* __restrict__ CB, float* __restrict__ c_sq,
             __bf16* __restrict__ cb16)
{
    const int wave = threadIdx.x >> 6;
    const int lane = threadIdx.x & 63;
    const int row = blockIdx.x * 4 + wave;
    const float* p = CB + (size_t)row * DD + lane * 8;
    const float4 a = *(const float4*)p;
    const float4 b = *(const float4*)(p + 4);
    bf16x8 h;
    h[0] = (__bf16)a.x; h[1] = (__bf16)a.y; h[2] = (__bf16)a.z; h[3] = (__bf16)a.w;
    h[4] = (__bf16)b.x; h[5] = (__bf16)b.y; h[6] = (__bf16)b.z; h[7] = (__bf16)b.w;
    *(bf16x8*)(cb16 + (size_t)row * DD + lane * 8) = h;
    float s = a.x*a.x + a.y*a.y + a.z*a.z + a.w*a.w
            + b.x*b.x + b.y*b.y + b.z*b.z + b.w*b.w;
    #pragma unroll
    for (int m = 1; m < 64; m <<= 1) s += __shfl_xor(s, m, 64);
    if (lane == 0) c_sq[row] = s;
}

// ---------------------------------------------------------------------------
extern "C" void kernel_launch(void* const* d_in, const int* in_sizes, int n_in,
                              void* d_out, int out_size, void* d_ws, size_t ws_size,
                              hipStream_t stream)
{
    const float* x    = (const float*)d_in[0];
    const float* encw = (const float*)d_in[1];
    const float* encb = (const float*)d_in[2];
    const float* cb   = (const float*)d_in[3];
    const float* decw = (const float*)d_in[4];
    const float* decb = (const float*)d_in[5];
    float* out = (float*)d_out;

    // ws layout: z (32MB) | r (32MB) | cb16 (16MB) | r16 (16MB, frag-major) | csq
    float* z    = (float*)d_ws;                                  // TT*DD f32
    float* r    = z + (size_t)TT * DD;                           // TT*DD f32
    __bf16* cb16 = (__bf16*)(r + (size_t)TT * DD);               // KK*512 bf16
    __bf16* r16  = cb16 + (size_t)KK * DD;                       // TT*512 bf16
    float* csq  = (float*)(r16 + (size_t)TT * DD);               // KK f32
    // winners table lives in d_out (33.5 MB) — dead before decoder writes out
    uint32_t* winners = (uint32_t*)d_out;                        // TT*512 u32

    const dim3 blk(256);

    // encoder (MFMA hi/lo): z = x @ enc_w^T + enc_b ; r = z ; r16 = bf16(z)
    gemm_mfma<0><<<dim3(DD / 128, TT / 128), blk, 0, stream>>>(
        x, nullptr, encw, encb, z, r, r16);

    // codebook: exact squared norms + bf16 copy (fused, once per call)
    prep_cb<<<dim3(KK / 4), blk, 0, stream>>>(cb, csq, cb16);

    for (int s = 0; s < 2; ++s) {
        // 2048 blocks = 128 code-tiles x 16 token-groups (CHAIN=8 tiles each);
        // 16 KB LDS + <=170 regs -> 3 blocks/CU; A direct-to-reg, coalesced.
        dist_approx4<<<dim3((KK / 128) * (TT / 128 / CHAIN)), dim3(256), 0, stream>>>(
            r16, cb16, csq, winners);
        select_rescore<<<dim3(TT / 4), blk, 0, stream>>>(winners, cb, csq, r, r16);
    }

    // decoder (MFMA hi/lo): out = (z - r) @ dec_w^T + dec_b
    gemm_mfma<1><<<dim3(DD / 128, TT / 128), blk, 0, stream>>>(
        z, r, decw, decb, out, nullptr, nullptr);
}